// Round 1
// 489.005 us; speedup vs baseline: 1.1207x; 1.1207x over previous
//
#include <hip/hip_runtime.h>
#include <stdint.h>
#include <stddef.h>

#define IN_F 4096
#define OUT_F 4096
#define M_TOT 8192

// fused-fallback tile
#define BM 128
#define BN 128
#define BK 64

// 8-phase main GEMM tile
#define BM2 256
#define BN2 256
#define BK2 64
#define NT2 (IN_F / BK2)   // 64 K-tiles

typedef __attribute__((ext_vector_type(8))) short short8;     // 8 x bf16 (4 VGPRs) MFMA A/B frag
typedef __attribute__((ext_vector_type(4))) float f32x4;      // MFMA C/D frag
typedef __attribute__((ext_vector_type(4))) float float4v;
typedef __attribute__((ext_vector_type(4))) unsigned short u16x4;
typedef __attribute__((ext_vector_type(8))) unsigned short u16x8;
typedef unsigned short u16;

// FP4 codebook (matches reference FP4_CODEBOOK exactly)
__constant__ float c_lut[16] = {
  0.0f, 0.0052f, 0.6667f, 1.0f, 0.3333f, 0.5f, 0.1667f, 0.25f,
  0.0f, -0.0052f, -0.6667f, -1.0f, -0.3333f, -0.5f, -0.1667f, -0.25f
};

// fp32 -> bf16 round-to-nearest-even
__device__ __forceinline__ u16 f2bf(float f) {
  unsigned int x = __float_as_uint(f);
  x += 0x7fffu + ((x >> 16) & 1u);
  return (u16)(x >> 16);
}

// async global->LDS, 16B per lane. LDS dest is wave-uniform base + lane*16.
__device__ __forceinline__ void gload_lds16(const u16* g, u16* lds) {
  __builtin_amdgcn_global_load_lds(
      (const __attribute__((address_space(1))) unsigned int*)g,
      (__attribute__((address_space(3))) unsigned int*)lds, 16, 0, 0);
}

// raw barrier (NO vmcnt drain — that drain is the m97-structure's 20% stall).
// asm memory fences stop the compiler moving LDS ops across the sync point.
#define BARRIER() do { asm volatile("" ::: "memory"); \
                       __builtin_amdgcn_s_barrier();  \
                       asm volatile("" ::: "memory"); } while (0)
#define LGKM0() asm volatile("s_waitcnt lgkmcnt(0)" ::: "memory")

// ---------------- prep kernel 1: x fp32 -> bf16 (M x K, k-major) ----------------
__global__ __launch_bounds__(256) void k_convert_x(const float* __restrict__ x,
                                                   u16* __restrict__ a) {
  const int n8 = (M_TOT * IN_F) / 8;   // u16x8 groups
  const int stride = gridDim.x * blockDim.x;
  for (int t = blockIdx.x * blockDim.x + threadIdx.x; t < n8; t += stride) {
    float4v f0 = ((const float4v*)x)[2 * t];
    float4v f1 = ((const float4v*)x)[2 * t + 1];
    u16x8 o;
    o[0] = f2bf(f0.x); o[1] = f2bf(f0.y); o[2] = f2bf(f0.z); o[3] = f2bf(f0.w);
    o[4] = f2bf(f1.x); o[5] = f2bf(f1.y); o[6] = f2bf(f1.z); o[7] = f2bf(f1.w);
    ((u16x8*)a)[t] = o;
  }
}

// ------------- prep kernel 2: packed fp4 -> bf16 W (N x K, k-major) -------------
__global__ __launch_bounds__(256) void k_dequant_w(const int* __restrict__ wp,
                                                   const float* __restrict__ scale,
                                                   u16* __restrict__ b) {
  __shared__ float lut[16];
  if (threadIdx.x < 16) lut[threadIdx.x] = c_lut[threadIdx.x];
  __syncthreads();
  const int ng = (OUT_F * IN_F / 2) / 4;  // int4 groups
  const int stride = gridDim.x * blockDim.x;
  for (int t = blockIdx.x * blockDim.x + threadIdx.x; t < ng; t += stride) {
    int4 p = ((const int4*)wp)[t];
    float s = scale[t >> 3];            // elements 8t..8t+7 share block t/8
    int by[4] = {p.x, p.y, p.z, p.w};
    u16x8 o;
#pragma unroll
    for (int q = 0; q < 4; ++q) {
      o[2 * q]     = f2bf(lut[(by[q] >> 4) & 15] * s);
      o[2 * q + 1] = f2bf(lut[by[q] & 15] * s);
    }
    ((u16x8*)b)[t] = o;
  }
}

// ===================== 256x256 8-phase pipelined GEMM =====================
// C = A(bf16, MxK) * B(bf16, NxK)^T + bias
// 512 thr / 8 waves (2M x 4N), per-wave output 128x64 (acc[8][4] 16x16 frags).
// LDS 128 KiB: As[2][256][64] + Bs[2][256][64], chunk-XOR swizzle
//   (LDS 16B-chunk p of row r holds GLOBAL chunk p ^ (r&7); reads use gc^(r&7)).
// Per K-tile: 4 phases, quadrant order (A0,B0)(A0,B1)(A1,B1)(A1,B0).
//   Each phase: ds_read one operand half | issue ONE half-tile stage (2 gload_lds)
//               | barrier | lgkmcnt(0) | setprio(1) 16xMFMA setprio(0) | barrier.
// Staging halves == compute halves, overwritten right after their last read:
//   P1 stages B0(t+1)->other buf; P2/P3/P4 stage A0/B1/A1(t+2)->current buf.
// vmcnt fence ONLY at each tile's P4: vmcnt(6) = 3 half-tiles (6 loads) in
// flight (never 0 in steady state); drains 0 for the last two tiles.

__device__ __forceinline__ void stage_a_half(const u16* __restrict__ A, u16* dst,
                                             int mBase, int kt, int h,
                                             int wave, int srow, int scol) {
#pragma unroll
  for (int n = 0; n < 2; ++n) {
    const int r0 = n * 128 + h * 64 + wave * 8;   // wave-uniform, multiple of 8
    gload_lds16(A + (size_t)(mBase + r0 + srow) * IN_F + kt + scol, dst + r0 * BK2);
  }
}

__device__ __forceinline__ void stage_b_half(const u16* __restrict__ B, u16* dst,
                                             int nBase, int kt, int jh,
                                             int wave, int srow, int scol) {
#pragma unroll
  for (int n = 0; n < 2; ++n) {
    const int slot = wave * 2 + n;                 // 0..15
    const int r0 = (slot >> 2) * 64 + jh * 32 + (slot & 3) * 8;
    gload_lds16(B + (size_t)(nBase + r0 + srow) * IN_F + kt + scol, dst + r0 * BK2);
  }
}

__device__ __forceinline__ void read_a4(const u16* As_c, int aBase, int co0, int co1,
                                        short8 a[4][2], int h) {
#pragma unroll
  for (int ii = 0; ii < 4; ++ii) {
    const int ro = aBase + (h * 4 + ii) * (16 * BK2);
    a[ii][0] = *(const short8*)&As_c[ro + co0];
    a[ii][1] = *(const short8*)&As_c[ro + co1];
  }
}

__device__ __forceinline__ void read_b2(const u16* Bs_c, int bBase, int co0, int co1,
                                        short8 b[2][2], int jh) {
#pragma unroll
  for (int jj = 0; jj < 2; ++jj) {
    const int ro = bBase + (jh * 2 + jj) * (16 * BK2);
    b[jj][0] = *(const short8*)&Bs_c[ro + co0];
    b[jj][1] = *(const short8*)&Bs_c[ro + co1];
  }
}

__device__ __forceinline__ void mma_quad(f32x4 acc[8][4], const short8 a[4][2],
                                         const short8 b[2][2], int h, int jh) {
#pragma unroll
  for (int k2 = 0; k2 < 2; ++k2)
#pragma unroll
    for (int ii = 0; ii < 4; ++ii)
#pragma unroll
      for (int jj = 0; jj < 2; ++jj)
        acc[h * 4 + ii][jh * 2 + jj] = __builtin_amdgcn_mfma_f32_16x16x32_bf16(
            a[ii][k2], b[jj][k2], acc[h * 4 + ii][jh * 2 + jj], 0, 0, 0);
}

__global__ __launch_bounds__(512, 2) void k_gemm256(const u16* __restrict__ A,
                                                    const u16* __restrict__ B,
                                                    const float* __restrict__ bias,
                                                    float* __restrict__ C) {
  __shared__ u16 As[2][BM2 * BK2];   // 2 x 32 KiB
  __shared__ u16 Bs[2][BN2 * BK2];   // 2 x 32 KiB

  const int tid  = threadIdx.x;
  const int lane = tid & 63;
  const int wave = tid >> 6;

  // XCD-aware tile swizzle: 8x8 tile square per XCD (grid 32x16, 512 wgs, %8==0)
  const int bid   = blockIdx.x;
  const int xcd   = bid & 7;
  const int k     = bid >> 3;                       // 0..63
  const int tileM = (xcd >> 1) * 8 + (k >> 3);      // 0..31
  const int tileN = (xcd & 1) * 8 + (k & 7);        // 0..15
  const int mBase = tileM * BM2;
  const int nBase = tileN * BN2;

  const int wm = (wave >> 2) * 128;                 // wave M base (0/128)
  const int wn = (wave & 3) * 64;                   // wave N base (0/64/128/192)

  // staging lane decomposition (8 rows x 64 cols per gload, XOR-swizzled source)
  const int srow = lane >> 3;                       // 0..7
  const int scol = ((lane & 7) ^ srow) * 8;         // swizzled k offset (elements)

  // MFMA operand addressing
  const int frow = lane & 15;
  const int fx   = frow & 7;                        // swizzle key
  const int cq   = lane >> 4;                       // k-quad id
  const int co0  = ((cq ^ fx) << 3);                // ks=0  chunk offset (elems)
  const int co1  = (((4 + cq) ^ fx) << 3);          // ks=32 chunk offset
  const int aBase = (wm + frow) * BK2;
  const int bBase = (wn + frow) * BK2;

  f32x4 acc[8][4] = {};

  // ---- prologue: tile0 fully + tile1 {A0,B1,A1}; keep 6 loads in flight ----
  stage_a_half(A, As[0], mBase, 0, 0, wave, srow, scol);
  stage_a_half(A, As[0], mBase, 0, 1, wave, srow, scol);
  stage_b_half(B, Bs[0], nBase, 0, 0, wave, srow, scol);
  stage_b_half(B, Bs[0], nBase, 0, 1, wave, srow, scol);
  stage_a_half(A, As[1], mBase, BK2, 0, wave, srow, scol);
  stage_b_half(B, Bs[1], nBase, BK2, 1, wave, srow, scol);
  stage_a_half(A, As[1], mBase, BK2, 1, wave, srow, scol);
  asm volatile("s_waitcnt vmcnt(6)" ::: "memory");  // tile0 landed
  BARRIER();

  short8 a[4][2], b[2][2];

#pragma unroll 2
  for (int t = 0; t < NT2; ++t) {
    const int c = t & 1;
    u16* AsC = As[c];
    u16* BsC = Bs[c];
    u16* BsO = Bs[c ^ 1];
    const int kt1 = (t + 1) * BK2;
    const int kt2 = (t + 2) * BK2;

    // ---- P1: quadrant (A0,B0); stage B0(t+1) -> other buf ----
    read_a4(AsC, aBase, co0, co1, a, 0);
    read_b2(BsC, bBase, co0, co1, b, 0);
    if (t + 1 < NT2) stage_b_half(B, BsO, nBase, kt1, 0, wave, srow, scol);
    BARRIER();
    LGKM0();
    __builtin_amdgcn_s_setprio(1);
    mma_quad(acc, a, b, 0, 0);
    __builtin_amdgcn_s_setprio(0);
    BARRIER();

    // ---- P2: quadrant (A0,B1); stage A0(t+2) -> current buf (freed in P1) ----
    read_b2(BsC, bBase, co0, co1, b, 1);
    if (t + 2 < NT2) stage_a_half(A, AsC, mBase, kt2, 0, wave, srow, scol);
    BARRIER();
    LGKM0();
    __builtin_amdgcn_s_setprio(1);
    mma_quad(acc, a, b, 0, 1);
    __builtin_amdgcn_s_setprio(0);
    BARRIER();

    // ---- P3: quadrant (A1,B1); stage B1(t+2) -> current buf (freed in P2) ----
    read_a4(AsC, aBase, co0, co1, a, 1);
    if (t + 2 < NT2) stage_b_half(B, BsC, nBase, kt2, 1, wave, srow, scol);
    BARRIER();
    LGKM0();
    __builtin_amdgcn_s_setprio(1);
    mma_quad(acc, a, b, 1, 1);
    __builtin_amdgcn_s_setprio(0);
    BARRIER();

    // ---- P4: quadrant (A1,B0); stage A1(t+2) -> current buf (freed in P3) ----
    read_b2(BsC, bBase, co0, co1, b, 0);
    if (t + 2 < NT2) stage_a_half(A, AsC, mBase, kt2, 1, wave, srow, scol);
    BARRIER();
    LGKM0();
    __builtin_amdgcn_s_setprio(1);
    mma_quad(acc, a, b, 1, 0);
    __builtin_amdgcn_s_setprio(0);
    // counted fence: next tile resident, 6 loads (3 half-tiles) stay in flight
    if (t < NT2 - 2) asm volatile("s_waitcnt vmcnt(6)" ::: "memory");
    else             asm volatile("s_waitcnt vmcnt(0)" ::: "memory");
    BARRIER();
  }

  // epilogue: C/D layout col = lane&15, row = (lane>>4)*4 + reg   [m89-verified]
  const int ccol = lane & 15;
  const int crow = (lane >> 4) * 4;
#pragma unroll
  for (int j = 0; j < 4; ++j) {
    const int col = nBase + wn + j * 16 + ccol;
    const float bv = bias[col];
#pragma unroll
    for (int i = 0; i < 8; ++i) {
      const size_t rb = (size_t)(mBase + wm + i * 16 + crow) * OUT_F + col;
#pragma unroll
      for (int tt = 0; tt < 4; ++tt)
        C[rb + (size_t)tt * OUT_F] = acc[i][j][tt] + bv;
    }
  }
}

// -------- fallback: fully fused (no workspace), register-staged conversion --------
__global__ __launch_bounds__(256) void k_gemm_fused(const float* __restrict__ X,
                                                    const int* __restrict__ WP,
                                                    const float* __restrict__ scale,
                                                    const float* __restrict__ bias,
                                                    float* __restrict__ C) {
  __shared__ u16 As[BM * BK];
  __shared__ u16 Bs[BN * BK];
  __shared__ float lut[16];
  const int tid = threadIdx.x;
  if (tid < 16) lut[tid] = c_lut[tid];
  const int lane = tid & 63;
  const int wave = tid >> 6;
  const int mBase = blockIdx.y * BM;
  const int nBase = blockIdx.x * BN;
  const int wm = (wave >> 1) * 64;
  const int wn = (wave & 1) * 64;
  const int frow = lane & 15;
  const int fx   = lane & 7;
  const int cq   = lane >> 4;
  f32x4 acc[4][4] = {};
  __syncthreads();  // lut ready

  for (int kt = 0; kt < IN_F; kt += BK) {
#pragma unroll
    for (int i = 0; i < 8; ++i) {
      const int g = tid + i * 256;
      const int r = g >> 4, c = (g & 15) * 4;
      float4v f = *(const float4v*)&X[(size_t)(mBase + r) * IN_F + kt + c];
      u16x4 o;
      o.x = f2bf(f.x); o.y = f2bf(f.y); o.z = f2bf(f.z); o.w = f2bf(f.w);
      *(u16x4*)&As[r * BK + ((((c >> 3) ^ (r & 7)) << 3) | (c & 7))] = o;
    }
#pragma unroll
    for (int i = 0; i < 4; ++i) {
      const int g = tid + i * 256;
      const int r = g >> 3, c4 = (g & 7) * 4;
      int4 p = *(const int4*)&WP[(size_t)(nBase + r) * (IN_F / 2) + (kt >> 1) + c4];
      const float s = scale[(nBase + r) * 64 + (kt >> 6)];
      int by[4] = {p.x, p.y, p.z, p.w};
      u16x8 o;
#pragma unroll
      for (int q = 0; q < 4; ++q) {
        o[2 * q]     = f2bf(lut[(by[q] >> 4) & 15] * s);
        o[2 * q + 1] = f2bf(lut[by[q] & 15] * s);
      }
      *(u16x8*)&Bs[r * BK + (((g & 7) ^ (r & 7)) << 3)] = o;
    }
    __syncthreads();
#pragma unroll
    for (int ks = 0; ks < BK; ks += 32) {
      const int co = (((ks >> 3) + cq) ^ fx) << 3;
      short8 a[4], b[4];
#pragma unroll
      for (int i = 0; i < 4; ++i)
        a[i] = *(const short8*)&As[(wm + i * 16 + frow) * BK + co];
#pragma unroll
      for (int j = 0; j < 4; ++j)
        b[j] = *(const short8*)&Bs[(wn + j * 16 + frow) * BK + co];
#pragma unroll
      for (int i = 0; i < 4; ++i)
#pragma unroll
        for (int j = 0; j < 4; ++j)
          acc[i][j] = __builtin_amdgcn_mfma_f32_16x16x32_bf16(a[i], b[j], acc[i][j], 0, 0, 0);
    }
    __syncthreads();
  }

  const int ccol = lane & 15;
  const int crow = (lane >> 4) * 4;
#pragma unroll
  for (int j = 0; j < 4; ++j) {
    const int col = nBase + wn + j * 16 + ccol;
    const float bv = bias[col];
#pragma unroll
    for (int i = 0; i < 4; ++i) {
      const size_t rb = (size_t)(mBase + wm + i * 16 + crow) * OUT_F + col;
#pragma unroll
      for (int t = 0; t < 4; ++t)
        C[rb + (size_t)t * OUT_F] = acc[i][j][t] + bv;
    }
  }
}

extern "C" void kernel_launch(void* const* d_in, const int* in_sizes, int n_in,
                              void* d_out, int out_size, void* d_ws, size_t ws_size,
                              hipStream_t stream) {
  const float* x  = (const float*)d_in[0];
  const int*   wp = (const int*)d_in[1];
  const float* sc = (const float*)d_in[2];
  const float* bi = (const float*)d_in[3];
  float* out = (float*)d_out;

  const size_t bBytes = (size_t)OUT_F * IN_F * 2;   // 33.5 MB bf16 W
  const size_t aBytes = (size_t)M_TOT * IN_F * 2;   // 67 MB bf16 x

  if (ws_size >= aBytes + bBytes) {
    u16* B = (u16*)d_ws;
    u16* A = (u16*)((char*)d_ws + bBytes);
    k_dequant_w<<<2048, 256, 0, stream>>>(wp, sc, B);
    k_convert_x<<<4096, 256, 0, stream>>>(x, A);
    k_gemm256<<<(M_TOT / BM2) * (OUT_F / BN2), 512, 0, stream>>>(A, B, bi, out);
  } else {
    dim3 grid(OUT_F / BN, M_TOT / BM);
    k_gemm_fused<<<grid, 256, 0, stream>>>(x, wp, sc, bi, out);
  }
}